// Round 6
// baseline (3271.251 us; speedup 1.0000x reference)
//
#include <hip/hip_runtime.h>

#define HD   1024      // hidden
#define G3   3072      // 3*H
#define ED   512       // embed
#define ZD   64        // latent dim (z)
#define VV   50257     // vocab
#define TT   64        // steps
#define BT   512
#define NBS  128       // persistent-step blocks (<= CU count, co-resident)

// ws layout (float offsets)
#define OFF_HINIT 0
#define OFF_HALL  1024
#define OFF_HALLT 66560      // 1024 + 64*1024
#define OFF_GI    132096     // + 1024*64
#define OFF_PMAX  135168     // 256 floats  [t][q]
#define OFF_PIDX  135424     // 256 ints
#define OFF_PSUM  135680     // 256 floats
#define OFF_CNT   135936     // 1 uint (spin-barrier counter)

// ---------------- K0: h0 = z@Wdec + bdec ; gi = Wih@eos + bih ; cnt=0 ----------------
__global__ __launch_bounds__(BT) void k_init(
    const float* __restrict__ z,    const float* __restrict__ eos,
    const float* __restrict__ Wih,  const float* __restrict__ bih,
    const float* __restrict__ Wdec, const float* __restrict__ bdec,
    float* __restrict__ ws)
{
    const int tid = threadIdx.x;
    const int b   = blockIdx.x;
    float* h_init = ws + OFF_HINIT;
    float* gi     = ws + OFF_GI;

    if (b == 0 && tid == 0) *(unsigned int*)(ws + OFF_CNT) = 0u;

    if (b == 384) {
        #pragma unroll
        for (int rep = 0; rep < 2; ++rep) {
            int j = tid + rep * BT;          // 0..1023
            float acc = bdec[j];
            #pragma unroll
            for (int i = 0; i < ZD; ++i)
                acc = fmaf(z[i], Wdec[i * HD + j], acc);   // Wdec is (64,1024)
            h_init[j] = acc;
        }
    } else {
        const int gtid = b * BT + tid;
        const int w    = gtid >> 6;          // 0..3071
        const int lane = tid & 63;
        const float* wp = Wih + (size_t)w * ED + lane;
        float d = 0.f;
        #pragma unroll
        for (int i = 0; i < 8; ++i) d = fmaf(wp[i * 64], eos[lane + i * 64], d);
        #pragma unroll
        for (int off = 32; off; off >>= 1) d += __shfl_xor(d, off, 64);
        if (lane == 0) gi[w] = d + bih[w];
    }
}

// ---------------- K_steps: all 64 GRU steps in one persistent kernel ----------------
// 128 blocks x 512 thr = 1024 waves; wave -> output row j (3 gate dots).
// Device-scope spin barrier per step (monotone counter). Whh slice per block is
// 96KB -> L2-resident after step 0 (Whh fetched from HBM exactly once).
__global__ __launch_bounds__(BT) void k_steps(
    const float* __restrict__ Whh, const float* __restrict__ bhh,
    float* __restrict__ ws)
{
    const int tid  = threadIdx.x;
    const int lane = tid & 63;
    const int w    = blockIdx.x * 8 + (tid >> 6);   // 0..1023

    float* h_init = ws + OFF_HINIT;
    float* h_all  = ws + OFF_HALL;
    float* h_allT = ws + OFF_HALLT;
    const float* gi = ws + OFF_GI;
    unsigned int* cnt = (unsigned int*)(ws + OFF_CNT);

    const float4* W4  = (const float4*)Whh;
    const float4* r0p = W4 + (size_t)w * 256 + lane * 4;
    const float4* r1p = W4 + (size_t)(w + HD) * 256 + lane * 4;
    const float4* r2p = W4 + (size_t)(w + 2 * HD) * 256 + lane * 4;

    const float g0 = gi[w], g1 = gi[w + HD], g2 = gi[w + 2 * HD];
    const float b0 = bhh[w], b1 = bhh[w + HD], b2 = bhh[w + 2 * HD];

    for (int t = 0; t < TT; ++t) {
        const float* hp   = (t == 0) ? h_init : (h_all + (size_t)(t - 1) * HD);
        const float4* hp4 = (const float4*)hp + lane * 4;

        float d0 = 0.f, d1 = 0.f, d2 = 0.f;
        #pragma unroll
        for (int j = 0; j < 4; ++j) {
            float4 hv = hp4[j];
            float4 a0 = r0p[j];
            float4 a1 = r1p[j];
            float4 a2 = r2p[j];
            d0 = fmaf(a0.x, hv.x, d0); d0 = fmaf(a0.y, hv.y, d0);
            d0 = fmaf(a0.z, hv.z, d0); d0 = fmaf(a0.w, hv.w, d0);
            d1 = fmaf(a1.x, hv.x, d1); d1 = fmaf(a1.y, hv.y, d1);
            d1 = fmaf(a1.z, hv.z, d1); d1 = fmaf(a1.w, hv.w, d1);
            d2 = fmaf(a2.x, hv.x, d2); d2 = fmaf(a2.y, hv.y, d2);
            d2 = fmaf(a2.z, hv.z, d2); d2 = fmaf(a2.w, hv.w, d2);
        }
        #pragma unroll
        for (int off = 32; off; off >>= 1) {
            d0 += __shfl_xor(d0, off, 64);
            d1 += __shfl_xor(d1, off, 64);
            d2 += __shfl_xor(d2, off, 64);
        }
        if (lane == 0) {
            float r = 1.f / (1.f + expf(-(g0 + d0 + b0)));
            float u = 1.f / (1.f + expf(-(g1 + d1 + b1)));
            float n = tanhf(g2 + r * (d2 + b2));
            float hn = (1.f - u) * n + u * hp[w];
            h_all[(size_t)t * HD + w]  = hn;
            h_allT[(size_t)w * TT + t] = hn;
        }
        // device-scope step barrier
        __threadfence();
        __syncthreads();
        if (tid == 0) {
            atomicAdd(cnt, 1u);
            while (__hip_atomic_load(cnt, __ATOMIC_ACQUIRE, __HIP_MEMORY_SCOPE_AGENT)
                   < (unsigned int)(NBS * (t + 1)))
                __builtin_amdgcn_s_sleep(1);
        }
        __syncthreads();
        __threadfence();
    }
}

// ---------------- K1: logits = h_all @ Wv + bv  (raw, into out) ----------------
// Barrier-free, LDS-free: h broadcast-read via L1/L2 (h_allT is 256KB, L2-hot).
// lane: kp = tid[0:1] (k-quarter), vgl = tid[2:5] (16 v-groups), tq = tid[6:8].
#define FMA4(ACC, S) do { ACC.x = fmaf(w4.x,(S),ACC.x); ACC.y = fmaf(w4.y,(S),ACC.y); \
                          ACC.z = fmaf(w4.z,(S),ACC.z); ACC.w = fmaf(w4.w,(S),ACC.w); } while(0)

__global__ __launch_bounds__(BT) void k_gemm(
    const float* __restrict__ Wv, const float* __restrict__ bv,
    const float* __restrict__ hT,         // h_allT: [k=1024][t=64]
    float* __restrict__ out)
{
    const int tid = threadIdx.x;
    const int kp  = tid & 3;                 // k-quarter (256 k each)
    const int vgl = (tid >> 2) & 15;         // local v-group
    const int tq  = tid >> 6;                // 0..7, wave-uniform
    const int t0  = tq << 3;
    const int vg  = blockIdx.x * 16 + vgl;   // 0..12575
    const int v0  = vg << 2;                 // 0..50300
    const bool fullv = (v0 + 3 < VV);
    const bool vx = (v0 < VV);

    float4 acc[8];
    #pragma unroll
    for (int i = 0; i < 8; ++i) acc[i] = make_float4(0.f, 0.f, 0.f, 0.f);

    const float4* hTb = (const float4*)hT + (t0 >> 2);   // + k*16 indexes row k
    const int kbase = kp * 256;

    #pragma unroll 4
    for (int kk = 0; kk < 256; ++kk) {
        const int k = kbase + kk;
        const float* wp = Wv + (size_t)k * VV + v0;
        float4 w4;
        if (fullv) { w4.x = wp[0]; w4.y = wp[1]; w4.z = wp[2]; w4.w = wp[3]; }
        else { w4.x = vx ? wp[0] : 0.f; w4.y = 0.f; w4.z = 0.f; w4.w = 0.f; }
        float4 ha = hTb[k * 16];
        float4 hb = hTb[k * 16 + 1];
        FMA4(acc[0], ha.x); FMA4(acc[1], ha.y); FMA4(acc[2], ha.z); FMA4(acc[3], ha.w);
        FMA4(acc[4], hb.x); FMA4(acc[5], hb.y); FMA4(acc[6], hb.z); FMA4(acc[7], hb.w);
    }

    // combine k-quarters (butterfly over kp bits 0-1)
    #pragma unroll
    for (int i = 0; i < 8; ++i) {
        float4 a = acc[i];
        a.x += __shfl_xor(a.x, 1, 64); a.y += __shfl_xor(a.y, 1, 64);
        a.z += __shfl_xor(a.z, 1, 64); a.w += __shfl_xor(a.w, 1, 64);
        a.x += __shfl_xor(a.x, 2, 64); a.y += __shfl_xor(a.y, 2, 64);
        a.z += __shfl_xor(a.z, 2, 64); a.w += __shfl_xor(a.w, 2, 64);
        acc[i] = a;
    }

    if (kp == 0) {
        float bx = 0.f, by = 0.f, bz = 0.f, bw = 0.f;
        if (fullv) { bx = bv[v0]; by = bv[v0 + 1]; bz = bv[v0 + 2]; bw = bv[v0 + 3]; }
        else if (vx) bx = bv[v0];
        #pragma unroll
        for (int tt = 0; tt < 8; ++tt) {
            float4 a = acc[tt];
            float* op = out + (size_t)(t0 + tt) * VV + v0;
            if (fullv) { op[0] = a.x + bx; op[1] = a.y + by; op[2] = a.z + bz; op[3] = a.w + bw; }
            else if (vx) { op[0] = a.x + bx; }
        }
    }
}

// ---------------- K2: per-(row,quarter) max/argmax (first-index ties) + sum(exp) ----------------
#define RSB 512
#define QCH 12576      // ceil(50257/4) rounded to x16
__global__ __launch_bounds__(RSB) void k_rowstat(
    const float* __restrict__ out,
    float* __restrict__ pMax, int* __restrict__ pIdx, float* __restrict__ pSum)
{
    const int t   = blockIdx.x >> 2;
    const int q   = blockIdx.x & 3;
    const int tid = threadIdx.x;
    const int start = q * QCH;
    const int end   = (start + QCH < VV) ? (start + QCH) : VV;
    const float* row = out + (size_t)t * VV;

    __shared__ float sm[RSB];
    __shared__ int   si[RSB];

    float m = -3.4e38f; int mi = start;
    for (int i = start + tid; i < end; i += RSB) {
        float v = row[i];
        if (v > m) { m = v; mi = i; }          // ascending -> first max per thread
    }
    sm[tid] = m; si[tid] = mi;
    __syncthreads();
    for (int s = RSB / 2; s; s >>= 1) {
        if (tid < s) {
            float om = sm[tid + s]; int oi = si[tid + s];
            if (om > sm[tid] || (om == sm[tid] && oi < si[tid])) { sm[tid] = om; si[tid] = oi; }
        }
        __syncthreads();
    }
    const float M = sm[0];
    const int   I = si[0];
    __syncthreads();

    float s = 0.f;
    for (int i = start + tid; i < end; i += RSB) s += expf(row[i] - M);
    sm[tid] = s;
    __syncthreads();
    for (int st = RSB / 2; st; st >>= 1) {
        if (tid < st) sm[tid] += sm[tid + st];
        __syncthreads();
    }
    if (tid == 0) { pMax[blockIdx.x] = M; pIdx[blockIdx.x] = I; pSum[blockIdx.x] = sm[0]; }
}

// ---------------- K3: combine partials; log_p = logit - lz ; write tokens ----------------
__global__ __launch_bounds__(BT) void k_final(
    const float* __restrict__ pMax, const int* __restrict__ pIdx,
    const float* __restrict__ pSum, float* __restrict__ out)
{
    __shared__ float s_lz[TT];
    const int tid  = threadIdx.x;
    const int gtid = blockIdx.x * BT + tid;
    if (tid < TT) {
        float M = -3.4e38f; int I = 0;
        #pragma unroll
        for (int q = 0; q < 4; ++q) {            // ascending q -> first-occurrence ties
            float m = pMax[tid * 4 + q];
            if (m > M) { M = m; I = pIdx[tid * 4 + q]; }
        }
        float S = 0.f;
        #pragma unroll
        for (int q = 0; q < 4; ++q)
            S += pSum[tid * 4 + q] * expf(pMax[tid * 4 + q] - M);
        s_lz[tid] = M + logf(S);
        if (blockIdx.x == 0) out[(size_t)TT * VV + tid] = (float)I;
    }
    __syncthreads();

    const int total  = TT * VV;          // 3216448
    const int stride = 393 * BT;         // 201216
    #pragma unroll
    for (int r = 0; r < 16; ++r) {
        int idx = gtid + r * stride;
        if (idx < total) {
            int t = idx / VV;
            out[idx] = out[idx] - s_lz[t];
        }
    }
}

extern "C" void kernel_launch(void* const* d_in, const int* in_sizes, int n_in,
                              void* d_out, int out_size, void* d_ws, size_t ws_size,
                              hipStream_t stream) {
    (void)in_sizes; (void)n_in; (void)out_size; (void)ws_size;
    const float* z    = (const float*)d_in[0];
    const float* eos  = (const float*)d_in[1];
    const float* Wih  = (const float*)d_in[2];
    const float* Whh  = (const float*)d_in[3];
    const float* bih  = (const float*)d_in[4];
    const float* bhh  = (const float*)d_in[5];
    const float* Wdec = (const float*)d_in[6];
    const float* bdec = (const float*)d_in[7];
    const float* Wv   = (const float*)d_in[8];
    const float* bv   = (const float*)d_in[9];
    float* out = (float*)d_out;
    float* ws  = (float*)d_ws;

    hipLaunchKernelGGL(k_init, dim3(385), dim3(BT), 0, stream,
                       z, eos, Wih, bih, Wdec, bdec, ws);
    hipLaunchKernelGGL(k_steps, dim3(NBS), dim3(BT), 0, stream, Whh, bhh, ws);
    hipLaunchKernelGGL(k_gemm, dim3(786), dim3(BT), 0, stream,
                       Wv, bv, ws + OFF_HALLT, out);
    hipLaunchKernelGGL(k_rowstat, dim3(256), dim3(RSB), 0, stream,
                       out, ws + OFF_PMAX, (int*)(ws + OFF_PIDX), ws + OFF_PSUM);
    hipLaunchKernelGGL(k_final, dim3(393), dim3(BT), 0, stream,
                       ws + OFF_PMAX, (const int*)(ws + OFF_PIDX), ws + OFF_PSUM, out);
}

// Round 7
// 2352.164 us; speedup vs baseline: 1.3907x; 1.3907x over previous
//
#include <hip/hip_runtime.h>

#define HD   1024      // hidden
#define G3   3072      // 3*H
#define ED   512       // embed
#define ZD   64        // latent dim (z)
#define VV   50257     // vocab
#define TT   64        // steps
#define BT   512
#define NBS  16        // persistent-step blocks (slot barrier parties)
#define GB   1024      // k_gemm block threads

// ws layout (float offsets)
#define OFF_HINIT 0
#define OFF_HALL  1024
#define OFF_HALLT 66560      // 1024 + 64*1024
#define OFF_GI    132096     // + 1024*64
#define OFF_PMAX  135168     // 256 floats  [t][q]
#define OFF_PIDX  135424     // 256 ints
#define OFF_PSUM  135680     // 256 floats
#define OFF_ARR   135936     // 16 arrival slots, 64B-strided (256 floats)

// ---------------- K0: h0 = z@Wdec + bdec ; gi = Wih@eos + bih ; zero arrivals ----------------
__global__ __launch_bounds__(BT) void k_init(
    const float* __restrict__ z,    const float* __restrict__ eos,
    const float* __restrict__ Wih,  const float* __restrict__ bih,
    const float* __restrict__ Wdec, const float* __restrict__ bdec,
    float* __restrict__ ws)
{
    const int tid = threadIdx.x;
    const int b   = blockIdx.x;
    float* h_init = ws + OFF_HINIT;
    float* gi     = ws + OFF_GI;

    if (b == 0 && tid < NBS) ((unsigned int*)(ws + OFF_ARR))[tid * 16] = 0u;

    if (b == 384) {
        #pragma unroll
        for (int rep = 0; rep < 2; ++rep) {
            int j = tid + rep * BT;          // 0..1023
            float acc = bdec[j];
            #pragma unroll
            for (int i = 0; i < ZD; ++i)
                acc = fmaf(z[i], Wdec[i * HD + j], acc);   // Wdec is (64,1024)
            h_init[j] = acc;
        }
    } else {
        const int gtid = b * BT + tid;
        const int w    = gtid >> 6;          // 0..3071
        const int lane = tid & 63;
        const float* wp = Wih + (size_t)w * ED + lane;
        float d = 0.f;
        #pragma unroll
        for (int i = 0; i < 8; ++i) d = fmaf(wp[i * 64], eos[lane + i * 64], d);
        #pragma unroll
        for (int off = 32; off; off >>= 1) d += __shfl_xor(d, off, 64);
        if (lane == 0) gi[w] = d + bih[w];
    }
}

// ---------------- K_steps: all 64 GRU steps, 16 persistent blocks ----------------
// Block covers 64 rows j (8 waves x 8 j). Slot barrier: arrival = release STORE to
// own 64B-padded slot (no RMW); 16 lanes of wave 0 each poll ONE slot (one
// wave-wide load per poll round). No polling/arrival line contention.
__global__ __launch_bounds__(BT) void k_steps(
    const float* __restrict__ Whh, const float* __restrict__ bhh,
    float* __restrict__ ws)
{
    const int tid  = threadIdx.x;
    const int lane = tid & 63;
    const int wv   = tid >> 6;                       // 0..7
    const int jbase = blockIdx.x * 64 + wv * 8;      // 8 rows per wave

    float* h_init = ws + OFF_HINIT;
    float* h_all  = ws + OFF_HALL;
    float* h_allT = ws + OFF_HALLT;
    const float* gi = ws + OFF_GI;
    unsigned int* arr = (unsigned int*)(ws + OFF_ARR);

    // hoist gate constants into regs (compile-time jj -> stays in VGPRs)
    float G0[8], G1[8], G2[8], B2[8];
    #pragma unroll
    for (int jj = 0; jj < 8; ++jj) {
        int j = jbase + jj;
        G0[jj] = gi[j]          + bhh[j];
        G1[jj] = gi[j + HD]     + bhh[j + HD];
        G2[jj] = gi[j + 2 * HD];
        B2[jj] = bhh[j + 2 * HD];
    }

    for (int t = 0; t < TT; ++t) {
        const float* hp = (t == 0) ? h_init : (h_all + (size_t)(t - 1) * HD);
        const float4* hp4 = (const float4*)hp + lane * 4;
        float4 hv0 = hp4[0], hv1 = hp4[1], hv2 = hp4[2], hv3 = hp4[3];

        #pragma unroll
        for (int jj = 0; jj < 8; ++jj) {
            const int j = jbase + jj;
            const float4* a0 = (const float4*)(Whh + (size_t)j * HD) + lane * 4;
            const float4* a1 = (const float4*)(Whh + (size_t)(j + HD) * HD) + lane * 4;
            const float4* a2 = (const float4*)(Whh + (size_t)(j + 2 * HD) * HD) + lane * 4;
            float d0 = 0.f, d1 = 0.f, d2 = 0.f;
            #pragma unroll
            for (int q = 0; q < 4; ++q) {
                float4 hq = (q == 0) ? hv0 : (q == 1) ? hv1 : (q == 2) ? hv2 : hv3;
                float4 A0 = a0[q], A1 = a1[q], A2 = a2[q];
                d0 = fmaf(A0.x, hq.x, d0); d0 = fmaf(A0.y, hq.y, d0);
                d0 = fmaf(A0.z, hq.z, d0); d0 = fmaf(A0.w, hq.w, d0);
                d1 = fmaf(A1.x, hq.x, d1); d1 = fmaf(A1.y, hq.y, d1);
                d1 = fmaf(A1.z, hq.z, d1); d1 = fmaf(A1.w, hq.w, d1);
                d2 = fmaf(A2.x, hq.x, d2); d2 = fmaf(A2.y, hq.y, d2);
                d2 = fmaf(A2.z, hq.z, d2); d2 = fmaf(A2.w, hq.w, d2);
            }
            #pragma unroll
            for (int off = 32; off; off >>= 1) {
                d0 += __shfl_xor(d0, off, 64);
                d1 += __shfl_xor(d1, off, 64);
                d2 += __shfl_xor(d2, off, 64);
            }
            if (lane == 0) {
                float r = 1.f / (1.f + expf(-(G0[jj] + d0)));
                float u = 1.f / (1.f + expf(-(G1[jj] + d1)));
                float n = tanhf(G2[jj] + r * (d2 + B2[jj]));
                float hn = (1.f - u) * n + u * hp[j];
                h_all[(size_t)t * HD + j]  = hn;
                h_allT[(size_t)j * TT + t] = hn;
            }
        }

        // slot barrier
        __threadfence();
        __syncthreads();
        if (tid == 0)
            __hip_atomic_store(&arr[blockIdx.x * 16], (unsigned int)(t + 1),
                               __ATOMIC_RELEASE, __HIP_MEMORY_SCOPE_AGENT);
        if (tid < NBS) {
            while (__hip_atomic_load(&arr[tid * 16], __ATOMIC_ACQUIRE,
                                     __HIP_MEMORY_SCOPE_AGENT) < (unsigned int)(t + 1))
                __builtin_amdgcn_s_sleep(2);
        }
        __syncthreads();
    }
}

// ---------------- K1: logits = h_all @ Wv + bv  (raw, into out) ----------------
// Wave's 64 lanes span v -> each Wv row read as one 1KB coalesced wave-load.
// thread = 4t x 4v, acc 16 VGPR, no LDS, no barriers, flat k-loop (unroll 8).
__global__ __launch_bounds__(GB) void k_gemm(
    const float* __restrict__ Wv, const float* __restrict__ bv,
    const float* __restrict__ hT,         // h_allT: [k=1024][t=64]
    float* __restrict__ out)
{
    const int tid   = threadIdx.x;
    const int vlane = tid & 63;
    const int tq    = tid >> 6;               // 0..15
    const int t0    = tq << 2;                // 4 t per thread
    const int v0    = blockIdx.x * 256 + (vlane << 2);
    const bool fullv = (v0 + 3 < VV);         // VV%4==1 -> only v0==50256 partial
    const bool vx    = (v0 < VV);

    float4 acc0 = make_float4(0.f, 0.f, 0.f, 0.f);
    float4 acc1 = acc0, acc2 = acc0, acc3 = acc0;

    const float*  wp  = Wv + v0;
    const float4* hp  = (const float4*)hT + tq;   // f4 index = k*16 + tq

    #pragma unroll 8
    for (int k = 0; k < HD; ++k) {
        float4 w4;
        if (fullv) {
            w4 = *(const float4*)wp;
        } else {
            w4 = make_float4(0.f, 0.f, 0.f, 0.f);
            if (vx) w4.x = wp[0];
        }
        float4 h4 = hp[(size_t)k * 16];
        acc0.x = fmaf(w4.x, h4.x, acc0.x); acc0.y = fmaf(w4.y, h4.x, acc0.y);
        acc0.z = fmaf(w4.z, h4.x, acc0.z); acc0.w = fmaf(w4.w, h4.x, acc0.w);
        acc1.x = fmaf(w4.x, h4.y, acc1.x); acc1.y = fmaf(w4.y, h4.y, acc1.y);
        acc1.z = fmaf(w4.z, h4.y, acc1.z); acc1.w = fmaf(w4.w, h4.y, acc1.w);
        acc2.x = fmaf(w4.x, h4.z, acc2.x); acc2.y = fmaf(w4.y, h4.z, acc2.y);
        acc2.z = fmaf(w4.z, h4.z, acc2.z); acc2.w = fmaf(w4.w, h4.z, acc2.w);
        acc3.x = fmaf(w4.x, h4.w, acc3.x); acc3.y = fmaf(w4.y, h4.w, acc3.y);
        acc3.z = fmaf(w4.z, h4.w, acc3.z); acc3.w = fmaf(w4.w, h4.w, acc3.w);
        wp += VV;
    }

    if (vx) {
        float4 b4;
        if (fullv) b4 = *(const float4*)(bv + v0);
        else       b4 = make_float4(bv[v0], 0.f, 0.f, 0.f);
        float4 r[4] = { acc0, acc1, acc2, acc3 };
        #pragma unroll
        for (int i = 0; i < 4; ++i) {
            float* op = out + (size_t)(t0 + i) * VV + v0;
            if (fullv) {
                float4 o = make_float4(r[i].x + b4.x, r[i].y + b4.y,
                                       r[i].z + b4.z, r[i].w + b4.w);
                *(float4*)op = o;
            } else {
                op[0] = r[i].x + b4.x;
            }
        }
    }
}

// ---------------- K2: per-(row,quarter) max/argmax (first-index ties) + sum(exp) ----------------
#define RSB 512
#define QCH 12576      // ceil(50257/4) rounded to x16
__global__ __launch_bounds__(RSB) void k_rowstat(
    const float* __restrict__ out,
    float* __restrict__ pMax, int* __restrict__ pIdx, float* __restrict__ pSum)
{
    const int t   = blockIdx.x >> 2;
    const int q   = blockIdx.x & 3;
    const int tid = threadIdx.x;
    const int start = q * QCH;
    const int end   = (start + QCH < VV) ? (start + QCH) : VV;
    const float* row = out + (size_t)t * VV;

    __shared__ float sm[RSB];
    __shared__ int   si[RSB];

    float m = -3.4e38f; int mi = start;
    for (int i = start + tid; i < end; i += RSB) {
        float v = row[i];
        if (v > m) { m = v; mi = i; }          // ascending -> first max per thread
    }
    sm[tid] = m; si[tid] = mi;
    __syncthreads();
    for (int s = RSB / 2; s; s >>= 1) {
        if (tid < s) {
            float om = sm[tid + s]; int oi = si[tid + s];
            if (om > sm[tid] || (om == sm[tid] && oi < si[tid])) { sm[tid] = om; si[tid] = oi; }
        }
        __syncthreads();
    }
    const float M = sm[0];
    const int   I = si[0];
    __syncthreads();

    float s = 0.f;
    for (int i = start + tid; i < end; i += RSB) s += expf(row[i] - M);
    sm[tid] = s;
    __syncthreads();
    for (int st = RSB / 2; st; st >>= 1) {
        if (tid < st) sm[tid] += sm[tid + st];
        __syncthreads();
    }
    if (tid == 0) { pMax[blockIdx.x] = M; pIdx[blockIdx.x] = I; pSum[blockIdx.x] = sm[0]; }
}

// ---------------- K3: combine partials; log_p = logit - lz ; write tokens ----------------
__global__ __launch_bounds__(BT) void k_final(
    const float* __restrict__ pMax, const int* __restrict__ pIdx,
    const float* __restrict__ pSum, float* __restrict__ out)
{
    __shared__ float s_lz[TT];
    const int tid  = threadIdx.x;
    const int gtid = blockIdx.x * BT + tid;
    if (tid < TT) {
        float M = -3.4e38f; int I = 0;
        #pragma unroll
        for (int q = 0; q < 4; ++q) {            // ascending q -> first-occurrence ties
            float m = pMax[tid * 4 + q];
            if (m > M) { M = m; I = pIdx[tid * 4 + q]; }
        }
        float S = 0.f;
        #pragma unroll
        for (int q = 0; q < 4; ++q)
            S += pSum[tid * 4 + q] * expf(pMax[tid * 4 + q] - M);
        s_lz[tid] = M + logf(S);
        if (blockIdx.x == 0) out[(size_t)TT * VV + tid] = (float)I;
    }
    __syncthreads();

    const int total  = TT * VV;          // 3216448
    const int stride = 393 * BT;         // 201216
    #pragma unroll
    for (int r = 0; r < 16; ++r) {
        int idx = gtid + r * stride;
        if (idx < total) {
            int t = idx / VV;
            out[idx] = out[idx] - s_lz[t];
        }
    }
}

extern "C" void kernel_launch(void* const* d_in, const int* in_sizes, int n_in,
                              void* d_out, int out_size, void* d_ws, size_t ws_size,
                              hipStream_t stream) {
    (void)in_sizes; (void)n_in; (void)out_size; (void)ws_size;
    const float* z    = (const float*)d_in[0];
    const float* eos  = (const float*)d_in[1];
    const float* Wih  = (const float*)d_in[2];
    const float* Whh  = (const float*)d_in[3];
    const float* bih  = (const float*)d_in[4];
    const float* bhh  = (const float*)d_in[5];
    const float* Wdec = (const float*)d_in[6];
    const float* bdec = (const float*)d_in[7];
    const float* Wv   = (const float*)d_in[8];
    const float* bv   = (const float*)d_in[9];
    float* out = (float*)d_out;
    float* ws  = (float*)d_ws;

    hipLaunchKernelGGL(k_init, dim3(385), dim3(BT), 0, stream,
                       z, eos, Wih, bih, Wdec, bdec, ws);
    hipLaunchKernelGGL(k_steps, dim3(NBS), dim3(BT), 0, stream, Whh, bhh, ws);
    hipLaunchKernelGGL(k_gemm, dim3(197), dim3(GB), 0, stream,
                       Wv, bv, ws + OFF_HALLT, out);
    hipLaunchKernelGGL(k_rowstat, dim3(256), dim3(RSB), 0, stream,
                       out, ws + OFF_PMAX, (int*)(ws + OFF_PIDX), ws + OFF_PSUM);
    hipLaunchKernelGGL(k_final, dim3(393), dim3(BT), 0, stream,
                       ws + OFF_PMAX, (const int*)(ws + OFF_PIDX), ws + OFF_PSUM, out);
}